// Round 12
// baseline (134.297 us; speedup 1.0000x reference)
//
#include <hip/hip_runtime.h>
#include <stdint.h>

#define BB 2
#define HH 16
#define TT 2048
#define DD 64
#define NHASH 4
#define NHALF 32   // num_buckets/2

// ---------------- Phase 1: compute packed bucket words ----------------
// grid: BB*HH*(TT/128) = 512 blocks x 256 threads = exactly 2 blocks/CU
// resident (64 KiB LDS) -> perfect packing, no tail. Wave = hash n; each
// wave runs the K-loop twice (64-token halves), acc[8][4] reused.
// rg-combine via 3-step shfl_xor butterfly (index tie-break = first
// occurrence); bucket bytes stored straight to global. Arithmetic
// (f64 acc, f32 compare) bit-identical to rounds 2-10 (absmax 0).
__global__ __launch_bounds__(256, 2) void lsh_buckets_kernel(
    const float* __restrict__ hs,    // [BB, TT, HH*DD]
    const float* __restrict__ rot,   // [HH, DD, NHASH, NHALF]
    uint32_t* __restrict__ words)    // [BB*HH*TT]
{
    __shared__ uint32_t lds[16384];            // 64 KiB
    float4* v4 = (float4*)lds;                 // [128 t][16 slots]     32 KiB
    float4* r4 = (float4*)(lds + 8192);        // [4 n][32 r][16 slots] 32 KiB

    const int blk  = blockIdx.x;
    const int bh   = blk >> 4;        // / (TT/128)
    const int tblk = blk & 15;
    const int b    = bh >> 4;
    const int h    = bh & 15;
    const int t0   = tblk * 128;
    const int tid  = threadIdx.x;
    const int n    = tid >> 6;        // wave = hash
    const int lane = tid & 63;
    const int tg   = lane >> 3;       // token group (8 tokens)
    const int rg   = lane & 7;        // r group (4 r's)

    // ---- stage v tile: [128 t][64 d] f32, slot = d4 ^ ((t>>3)&7) ----
    #pragma unroll
    for (int p = 0; p < 8; ++p) {
        const int k  = tid + p * 256;       // 0..2047 float4s
        const int t  = k >> 4;
        const int d4 = k & 15;
        const float4 f = ((const float4*)(hs + ((size_t)(b * TT + t0 + t)) * (HH * DD) + h * DD))[d4];
        v4[t * 16 + (d4 ^ ((t >> 3) & 7))] = f;
    }
    // ---- stage rot: [4 n][32 r][64 d] f32, slot = d4 ^ (r>>2) ----
    {
        const float* rh = rot + (size_t)h * (DD * NHASH * NHALF);
        float* rf = (float*)r4;
        #pragma unroll
        for (int p = 0; p < 32; ++p) {
            const int g  = tid + p * 256;   // d*128 + n*32 + r (coalesced)
            const int d  = g >> 7;
            const int nr = g & 127;
            const int nn = nr >> 5;
            const int r  = nr & 31;
            const int slot = (d >> 2) ^ (r >> 2);
            rf[((nn * 32 + r) * 16 + slot) * 4 + (d & 3)] = rh[g];
        }
    }
    __syncthreads();

    const int rbase = (n * 32 + rg * 4) * 16;   // float4 idx of first own r row
    const int r0    = rg * 4;

    #pragma unroll
    for (int half = 0; half < 2; ++half) {
        const int th0   = half * 64;
        const int vbase = (th0 + tg * 8) * 16;

        // ---- K loop: acc[i][j] (t = th0+tg*8+i, r = rg*4+j), f64 ----
        double acc[8][4];
        #pragma unroll
        for (int i = 0; i < 8; ++i)
            #pragma unroll
            for (int j = 0; j < 4; ++j) acc[i][j] = 0.0;

        for (int s = 0; s < 16; ++s) {          // d = s*4 .. s*4+3
            double rd[4][4];
            #pragma unroll
            for (int j = 0; j < 4; ++j) {
                const float4 rf = r4[rbase + j * 16 + (s ^ rg)];
                rd[j][0] = (double)rf.x; rd[j][1] = (double)rf.y;
                rd[j][2] = (double)rf.z; rd[j][3] = (double)rf.w;
            }
            #pragma unroll
            for (int i = 0; i < 8; ++i) {
                const float4 vf = v4[vbase + i * 16 + (s ^ tg)];
                const double v0 = (double)vf.x, v1 = (double)vf.y;
                const double v2 = (double)vf.z, v3 = (double)vf.w;
                #pragma unroll
                for (int j = 0; j < 4; ++j) {
                    acc[i][j] += v0 * rd[j][0];
                    acc[i][j] += v1 * rd[j][1];
                    acc[i][j] += v2 * rd[j][2];
                    acc[i][j] += v3 * rd[j][3];
                }
            }
        }

        // ---- reduce: lane-local over j, then rg-butterfly (idx tie-break) ----
        #pragma unroll
        for (int i = 0; i < 8; ++i) {
            float fmx = -INFINITY; int imx = 0;
            float fmn =  INFINITY; int imn = 0;
            #pragma unroll
            for (int j = 0; j < 4; ++j) {
                const float f = (float)acc[i][j];
                const int   r = r0 + j;
                if (f > fmx) { fmx = f; imx = r; }
                if (f < fmn) { fmn = f; imn = r; }
            }
            #pragma unroll
            for (int off = 1; off < 8; off <<= 1) {
                const float px = __shfl_xor(fmx, off);
                const int   pi = __shfl_xor(imx, off);
                const float qx = __shfl_xor(fmn, off);
                const int   qi = __shfl_xor(imn, off);
                if (px > fmx || (px == fmx && pi < imx)) { fmx = px; imx = pi; }
                if (qx < fmn || (qx == fmn && qi < imn)) { fmn = qx; imn = qi; }
            }
            if (rg == 0) {
                const uint32_t bucket = (fmx >= -fmn) ? (uint32_t)imx : (uint32_t)(NHALF + imn);
                ((uint8_t*)words)[((size_t)bh * TT + t0 + th0 + tg * 8 + i) * 4 + n] = (uint8_t)bucket;
            }
        }
    }
}

// ---------------- Phase 2: materialize the [B,H,T,T] mask (int32 0/1) ----------------
// ROWS=32, 512-thread blocks (round-10 winner: P2 ~= 92 us, 5.8 TB/s).
#define ROWS 32
__device__ __forceinline__ uint32_t eq_any_byte(uint32_t a, uint32_t b) {
    const uint32_t x = a ^ b;
    return ((x - 0x01010101u) & ~x & 0x80808080u) ? 1u : 0u;
}

__global__ __launch_bounds__(512) void lsh_mask_kernel(
    const uint32_t* __restrict__ words,  // [BB*HH*TT]
    uint4* __restrict__ out)             // [BB*HH*TT][TT/4]
{
    const int bh  = blockIdx.x >> 6;            // TT/ROWS = 64 blocks per bh
    const int i0  = (blockIdx.x & 63) * ROWS;
    const int tid = threadIdx.x;                // 0..511, one uint4 of wj
    const uint32_t* wrow = words + (bh << 11);

    const uint4 wj = ((const uint4*)wrow)[tid];

    uint4* op = out + (((size_t)((bh << 11) + i0)) << 9) + tid;
    #pragma unroll
    for (int k = 0; k < ROWS; ++k) {
        const uint32_t wi = wrow[i0 + k];
        uint4 r;
        r.x = eq_any_byte(wi, wj.x); r.y = eq_any_byte(wi, wj.y);
        r.z = eq_any_byte(wi, wj.z); r.w = eq_any_byte(wi, wj.w);
        op[(size_t)k << 9] = r;
    }
}

extern "C" void kernel_launch(void* const* d_in, const int* in_sizes, int n_in,
                              void* d_out, int out_size, void* d_ws, size_t ws_size,
                              hipStream_t stream) {
    const float* hs  = (const float*)d_in[0];   // [2, 2048, 1024] f32
    const float* rot = (const float*)d_in[1];   // [16, 64, 4, 32] f32
    uint32_t* words  = (uint32_t*)d_ws;         // needs BB*HH*TT*4 = 256 KiB

    lsh_buckets_kernel<<<BB * HH * (TT / 128), 256, 0, stream>>>(hs, rot, words);
    lsh_mask_kernel<<<BB * HH * (TT / ROWS), 512, 0, stream>>>(words, (uint4*)d_out);
}

// Round 13
// 126.493 us; speedup vs baseline: 1.0617x; 1.0617x over previous
//
#include <hip/hip_runtime.h>
#include <stdint.h>

#define BB 2
#define HH 16
#define TT 2048
#define DD 64
#define NHASH 4
#define NHALF 32   // num_buckets/2

// ---------------- Phase 1: compute packed bucket words ----------------
// (exact round-6 kernel — best known; P1 ~= 30 us + launch overhead.
//  f64 accumulation + f32 compare + first-index tie-break: absmax 0 in
//  rounds 2-12. Dword pack via LDS — byte global stores regressed (r7/r12).)
__global__ __launch_bounds__(256, 3) void lsh_buckets_kernel(
    const float* __restrict__ hs,    // [BB, TT, HH*DD]
    const float* __restrict__ rot,   // [HH, DD, NHASH, NHALF]
    uint32_t* __restrict__ words)    // [BB*HH*TT]
{
    __shared__ uint32_t lds[12288];            // 48 KiB
    float4* v4 = (float4*)lds;                 // [64 t][16 slots]   (16 KiB)
    float4* r4 = (float4*)(lds + 4096);        // [4 n][32 r][16 slots] (32 KiB)

    const int blk  = blockIdx.x;
    const int bh   = blk >> 5;        // / (TT/64)
    const int tblk = blk & 31;
    const int b    = bh >> 4;
    const int h    = bh & 15;
    const int t0   = tblk * 64;
    const int tid  = threadIdx.x;
    const int n    = tid >> 6;        // wave = hash
    const int lane = tid & 63;
    const int tg   = lane >> 3;       // token group (8 tokens)
    const int rg   = lane & 7;        // r group (4 r's)

    // ---- stage v tile: [64 t][64 d] f32, slot = d4 ^ (t>>3) ----
    #pragma unroll
    for (int p = 0; p < 4; ++p) {
        const int k  = tid + p * 256;       // 0..1023 float4s
        const int t  = k >> 4;
        const int d4 = k & 15;
        const float4 f = ((const float4*)(hs + ((size_t)(b * TT + t0 + t)) * (HH * DD) + h * DD))[d4];
        v4[t * 16 + (d4 ^ (t >> 3))] = f;
    }
    // ---- stage rot: [4 n][32 r][64 d] f32, slot = d4 ^ (r>>2) ----
    {
        const float* rh = rot + (size_t)h * (DD * NHASH * NHALF);
        float* rf = (float*)r4;
        #pragma unroll
        for (int p = 0; p < 32; ++p) {
            const int g  = tid + p * 256;   // global idx: d*128 + n*32 + r (coalesced)
            const int d  = g >> 7;
            const int nr = g & 127;
            const int nn = nr >> 5;
            const int r  = nr & 31;
            const int slot = (d >> 2) ^ (r >> 2);
            rf[((nn * 32 + r) * 16 + slot) * 4 + (d & 3)] = rh[g];
        }
    }
    __syncthreads();

    // ---- K loop: acc[i][j] (t = tg*8+i, r = rg*4+j), f64 ----
    double acc[8][4];
    #pragma unroll
    for (int i = 0; i < 8; ++i)
        #pragma unroll
        for (int j = 0; j < 4; ++j) acc[i][j] = 0.0;

    const int vbase = tg * 8 * 16;                 // float4 index of first own token row
    const int rbase = (n * 32 + rg * 4) * 16;      // float4 index of first own r row

    for (int s = 0; s < 16; ++s) {                 // d = s*4 .. s*4+3
        double rd[4][4];
        #pragma unroll
        for (int j = 0; j < 4; ++j) {
            const float4 rf = r4[rbase + j * 16 + (s ^ rg)];
            rd[j][0] = (double)rf.x; rd[j][1] = (double)rf.y;
            rd[j][2] = (double)rf.z; rd[j][3] = (double)rf.w;
        }
        #pragma unroll
        for (int i = 0; i < 8; ++i) {
            const float4 vf = v4[vbase + i * 16 + (s ^ tg)];
            const double v0 = (double)vf.x, v1 = (double)vf.y;
            const double v2 = (double)vf.z, v3 = (double)vf.w;
            #pragma unroll
            for (int j = 0; j < 4; ++j) {
                acc[i][j] += v0 * rd[j][0];
                acc[i][j] += v1 * rd[j][1];
                acc[i][j] += v2 * rd[j][2];
                acc[i][j] += v3 * rd[j][3];
            }
        }
    }

    // ---- epilogue: argmax/argmin over r per (n,t) ----
    __syncthreads();   // all LDS reads done; alias lds for partials
    float*    vmaxL = (float*)lds;            // [4][64][9]
    float*    vminL = (float*)(lds + 2304);
    uint32_t* imaxL = lds + 4608;
    uint32_t* iminL = lds + 6912;
    uint32_t* bkt   = lds + 9216;             // [4][64]

    #pragma unroll
    for (int i = 0; i < 8; ++i) {
        const int t = tg * 8 + i;
        float fmx = -INFINITY; int imx = 0;
        float fmn =  INFINITY; int imn = 0;
        #pragma unroll
        for (int j = 0; j < 4; ++j) {
            const float f = (float)acc[i][j];
            const int   r = rg * 4 + j;
            if (f > fmx) { fmx = f; imx = r; }
            if (f < fmn) { fmn = f; imn = r; }
        }
        const int o = (n * 64 + t) * 9 + rg;
        vmaxL[o] = fmx; vminL[o] = fmn;
        imaxL[o] = (uint32_t)imx; iminL[o] = (uint32_t)imn;
    }
    __syncthreads();
    {
        const int nn = tid >> 6;
        const int t  = tid & 63;
        float fmx = -INFINITY; int imx = 0;
        float fmn =  INFINITY; int imn = 0;
        #pragma unroll
        for (int g = 0; g < 8; ++g) {     // rg ascending -> r ascending: first-index tie-break
            const int o = (nn * 64 + t) * 9 + g;
            const float fx = vmaxL[o];
            const float fn = vminL[o];
            if (fx > fmx) { fmx = fx; imx = (int)imaxL[o]; }
            if (fn < fmn) { fmn = fn; imn = (int)iminL[o]; }
        }
        const uint32_t bucket = (fmx >= -fmn) ? (uint32_t)imx : (uint32_t)(NHALF + imn);
        bkt[nn * 64 + t] = bucket;
    }
    __syncthreads();
    if (tid < 64) {
        words[(size_t)bh * TT + t0 + tid] = bkt[tid]
                                          | (bkt[64  + tid] << 8)
                                          | (bkt[128 + tid] << 16)
                                          | (bkt[192 + tid] << 24);
    }
}

// ---------------- Phase 2: materialize the [B,H,T,T] mask (int32 0/1) ----------------
// ROWS=32, 512-thread blocks (round-10 winner: P2 ~= 92 us, 5.8 TB/s).
#define ROWS 32
__device__ __forceinline__ uint32_t eq_any_byte(uint32_t a, uint32_t b) {
    const uint32_t x = a ^ b;
    return ((x - 0x01010101u) & ~x & 0x80808080u) ? 1u : 0u;
}

__global__ __launch_bounds__(512) void lsh_mask_kernel(
    const uint32_t* __restrict__ words,  // [BB*HH*TT]
    uint4* __restrict__ out)             // [BB*HH*TT][TT/4]
{
    const int bh  = blockIdx.x >> 6;            // TT/ROWS = 64 blocks per bh
    const int i0  = (blockIdx.x & 63) * ROWS;
    const int tid = threadIdx.x;                // 0..511, one uint4 of wj
    const uint32_t* wrow = words + (bh << 11);

    const uint4 wj = ((const uint4*)wrow)[tid];

    uint4* op = out + (((size_t)((bh << 11) + i0)) << 9) + tid;
    #pragma unroll
    for (int k = 0; k < ROWS; ++k) {
        const uint32_t wi = wrow[i0 + k];
        uint4 r;
        r.x = eq_any_byte(wi, wj.x); r.y = eq_any_byte(wi, wj.y);
        r.z = eq_any_byte(wi, wj.z); r.w = eq_any_byte(wi, wj.w);
        op[(size_t)k << 9] = r;
    }
}

extern "C" void kernel_launch(void* const* d_in, const int* in_sizes, int n_in,
                              void* d_out, int out_size, void* d_ws, size_t ws_size,
                              hipStream_t stream) {
    const float* hs  = (const float*)d_in[0];   // [2, 2048, 1024] f32
    const float* rot = (const float*)d_in[1];   // [16, 64, 4, 32] f32
    uint32_t* words  = (uint32_t*)d_ws;         // needs BB*HH*TT*4 = 256 KiB

    lsh_buckets_kernel<<<BB * HH * (TT / 64), 256, 0, stream>>>(hs, rot, words);
    lsh_mask_kernel<<<BB * HH * (TT / ROWS), 512, 0, stream>>>(words, (uint4*)d_out);
}